// Round 3
// baseline (113889.758 us; speedup 1.0000x reference)
//
#include <hip/hip_runtime.h>

typedef _Float16 f16x2 __attribute__((ext_vector_type(2)));
typedef _Float16 f16x8 __attribute__((ext_vector_type(8)));

#define B 64
#define T 2048
#define D 128
#define H 256
#define H2 512
#define CHUNK 8

__device__ __forceinline__ float sigmoid_f(float x) {
    return 1.f / (1.f + __expf(-x));
}
__device__ __forceinline__ float tanh_f(float x) {
    float e = __expf(2.f * x);          // overflow -> inf -> 1; underflow -> 0 -> -1
    return 1.f - 2.f / (e + 1.f);
}

// ---- pack K2 (512x256 fp32) -> f16 pairs along k: word (k2,j) = {K2[2k2][j], K2[2k2+1][j]} ----
__global__ __launch_bounds__(256) void pack_k2_kernel(
    const float* __restrict__ K2, f16x2* __restrict__ K2h)
{
    int idx = blockIdx.x * 256 + threadIdx.x;   // 65536
    int k2 = idx >> 8, j = idx & 255;
    f16x2 v;
    v.x = (_Float16)K2[(2 * k2) * H + j];
    v.y = (_Float16)K2[(2 * k2 + 1) * H + j];
    K2h[(size_t)k2 * H + j] = v;
}

// One block per batch row, 1024 threads.
// U fp32 resident in VGPRs (256/thread), K1 fp32 resident (128/thread),
// K2 f16 streamed (256KB/step), W streamed once per 8-step chunk via LDS xw buffer.
__global__ __launch_bounds__(1024, 1) void scan_kernel(
    const float* __restrict__ x,
    const float* __restrict__ Wi, const float* __restrict__ bi,
    const float* __restrict__ Wf, const float* __restrict__ bf,
    const float* __restrict__ Wc, const float* __restrict__ bc,
    const float* __restrict__ Wo, const float* __restrict__ bo,
    const float* __restrict__ Ui, const float* __restrict__ Uf,
    const float* __restrict__ Uc, const float* __restrict__ Uo,
    const float* __restrict__ K1, const float* __restrict__ kb1,
    const _Float16* __restrict__ K2h, const float* __restrict__ kb2,
    const float* __restrict__ gamma, const float* __restrict__ beta,
    float* __restrict__ out)
{
    const int b   = blockIdx.x;
    const int tid = threadIdx.x;

    // ---- roles ----
    const int qG  = tid >> 8;          // 0..3   : k-quarter for gates / d-quarter for P
    const int grp = tid & 255;         //        : (gate, col) group
    const int gG  = grp >> 6;          // 0..3   : gate
    const int jc  = (grp & 63) * 4;    //        : col within gate
    const int q1  = tid >> 7;          // 0..7   : k-slice for K1
    const int m4  = (tid & 127) * 4;   //        : K1 col group
    const int q2  = tid >> 6;          // 0..15  : k-slice for K2
    const int j4K = (tid & 63) * 4;    //        : K2 col group

    __shared__ float xwbuf[CHUNK][4 * H];  // 32 KB: xW+b for the current 8-step chunk
    __shared__ float red[4096];            // 16 KB: union pG[4][1024] / p1[8][512] / p2[16][256]
    __shared__ float hs[H], cs[H], gos[H], ts[H2];

    // ---- resident weights ----
    const float* Ug = (gG == 0) ? Ui : (gG == 1) ? Uf : (gG == 2) ? Uc : Uo;
    const float* Wg = (gG == 0) ? Wi : (gG == 1) ? Wf : (gG == 2) ? Wc : Wo;

    float4 uw[64];
    #pragma unroll
    for (int k = 0; k < 64; ++k)
        uw[k] = *(const float4*)(Ug + (size_t)(qG * 64 + k) * H + jc);

    float4 k1w[32];
    #pragma unroll
    for (int k = 0; k < 32; ++k)
        k1w[k] = *(const float4*)(K1 + (size_t)(q1 * 32 + k) * H2 + m4);

    // ---- per-role constants ----
    {
        const int g = tid >> 8, j = tid & 255;
        const float* bp = (g == 0) ? bi : (g == 1) ? bf : (g == 2) ? bc : bo;
        // bcat loaded below into register via bp[j]
        (void)bp;
    }
    const float* bpt = (tid >> 8) == 0 ? bi : (tid >> 8) == 1 ? bf : (tid >> 8) == 2 ? bc : bo;
    const float bcat = bpt[tid & 255];
    const float kb1r = (tid < H2) ? kb1[tid] : 0.f;
    float4 kb24, gam4, bet4;
    if (tid < 64) {
        kb24 = *(const float4*)(kb2 + tid * 4);
        gam4 = *(const float4*)(gamma + tid * 4);
        bet4 = *(const float4*)(beta + tid * 4);
    }

    if (tid < H) { hs[tid] = 0.f; cs[tid] = 0.f; }

    const float* xrow = x + (size_t)b * T * D;
    float* yb = out + (size_t)b * T * H;
    const int qGu = __builtin_amdgcn_readfirstlane(qG);  // force wave-uniform -> s_loads for x

    __syncthreads();

    for (int t = 0; t < T; ++t) {
        const int tt8 = t & (CHUNK - 1);

        // ================= phase P: xW for the next 8 steps (once per chunk) =================
        if (tt8 == 0) {
            float4 acc[CHUNK];
            #pragma unroll
            for (int r = 0; r < CHUNK; ++r) acc[r] = make_float4(0.f, 0.f, 0.f, 0.f);

            const float* Wp  = Wg + (size_t)(qG * 32) * H + jc;
            const float* xpd = xrow + (size_t)t * D + qGu * 32;   // wave-uniform base

            #pragma unroll 4
            for (int d = 0; d < 32; ++d) {
                float4 w = *(const float4*)(Wp + (size_t)d * H);  // streamed once per chunk
                #pragma unroll
                for (int r = 0; r < CHUNK; ++r) {
                    float xv = xpd[r * D + d];                    // uniform -> scalar load
                    acc[r].x = fmaf(xv, w.x, acc[r].x);
                    acc[r].y = fmaf(xv, w.y, acc[r].y);
                    acc[r].z = fmaf(xv, w.z, acc[r].z);
                    acc[r].w = fmaf(xv, w.w, acc[r].w);
                }
            }
            // reduce the 4 d-quarters, one tt at a time
            #pragma unroll
            for (int r = 0; r < CHUNK; ++r) {
                *(float4*)&red[qG * 1024 + grp * 4] = acc[r];
                __syncthreads();
                xwbuf[r][tid] = bcat + red[tid] + red[1024 + tid] + red[2048 + tid] + red[3072 + tid];
                __syncthreads();
            }
        }

        // ================= phase G: gate pre-activations (U part, register-resident) =========
        {
            float4 a = make_float4(0.f, 0.f, 0.f, 0.f);
            #pragma unroll
            for (int k4 = 0; k4 < 16; ++k4) {
                float4 hv = *(const float4*)&hs[qG * 64 + k4 * 4];  // LDS broadcast
                float4 w0 = uw[k4 * 4 + 0], w1 = uw[k4 * 4 + 1];
                float4 w2 = uw[k4 * 4 + 2], w3 = uw[k4 * 4 + 3];
                a.x = fmaf(hv.x, w0.x, a.x); a.y = fmaf(hv.x, w0.y, a.y);
                a.z = fmaf(hv.x, w0.z, a.z); a.w = fmaf(hv.x, w0.w, a.w);
                a.x = fmaf(hv.y, w1.x, a.x); a.y = fmaf(hv.y, w1.y, a.y);
                a.z = fmaf(hv.y, w1.z, a.z); a.w = fmaf(hv.y, w1.w, a.w);
                a.x = fmaf(hv.z, w2.x, a.x); a.y = fmaf(hv.z, w2.y, a.y);
                a.z = fmaf(hv.z, w2.z, a.z); a.w = fmaf(hv.z, w2.w, a.w);
                a.x = fmaf(hv.w, w3.x, a.x); a.y = fmaf(hv.w, w3.y, a.y);
                a.z = fmaf(hv.w, w3.z, a.z); a.w = fmaf(hv.w, w3.w, a.w);
            }
            *(float4*)&red[qG * 1024 + grp * 4] = a;
        }
        __syncthreads();

        // ---- gate combine + activations + cell update (256 threads, col j each) ----
        if (tid < 256) {
            const int j = tid;
            float pre[4];
            #pragma unroll
            for (int g = 0; g < 4; ++g) {
                const int col = g * 256 + j;
                pre[g] = xwbuf[tt8][col] + red[col] + red[1024 + col] + red[2048 + col] + red[3072 + col];
            }
            float ig = sigmoid_f(pre[0]);
            float fg = sigmoid_f(pre[1]);
            float gg = tanh_f(pre[2]);
            float og = sigmoid_f(pre[3]);
            float c  = fmaf(fg, cs[j], ig * gg);
            cs[j]  = c;
            gos[j] = og;
        }
        __syncthreads();

        // ================= phase K1: ts = tanh(c @ K1 + kb1) (register-resident) =============
        {
            float4 a = make_float4(0.f, 0.f, 0.f, 0.f);
            #pragma unroll
            for (int k4 = 0; k4 < 8; ++k4) {
                float4 cv = *(const float4*)&cs[q1 * 32 + k4 * 4];  // LDS broadcast
                float4 w0 = k1w[k4 * 4 + 0], w1 = k1w[k4 * 4 + 1];
                float4 w2 = k1w[k4 * 4 + 2], w3 = k1w[k4 * 4 + 3];
                a.x = fmaf(cv.x, w0.x, a.x); a.y = fmaf(cv.x, w0.y, a.y);
                a.z = fmaf(cv.x, w0.z, a.z); a.w = fmaf(cv.x, w0.w, a.w);
                a.x = fmaf(cv.y, w1.x, a.x); a.y = fmaf(cv.y, w1.y, a.y);
                a.z = fmaf(cv.y, w1.z, a.z); a.w = fmaf(cv.y, w1.w, a.w);
                a.x = fmaf(cv.z, w2.x, a.x); a.y = fmaf(cv.z, w2.y, a.y);
                a.z = fmaf(cv.z, w2.z, a.z); a.w = fmaf(cv.z, w2.w, a.w);
                a.x = fmaf(cv.w, w3.x, a.x); a.y = fmaf(cv.w, w3.y, a.y);
                a.z = fmaf(cv.w, w3.z, a.z); a.w = fmaf(cv.w, w3.w, a.w);
            }
            *(float4*)&red[q1 * 512 + m4] = a;
        }
        __syncthreads();
        if (tid < H2) {
            float s = kb1r;
            #pragma unroll
            for (int q = 0; q < 8; ++q) s += red[q * 512 + tid];
            ts[tid] = tanh_f(s);
        }
        __syncthreads();

        // ================= phase K2: h_pre = ts @ K2 (f16 weights streamed, fp32 acts) ========
        {
            float4 a = make_float4(0.f, 0.f, 0.f, 0.f);
            const _Float16* K2p = K2h + ((size_t)(q2 * 16) * H + j4K) * 2;
            #pragma unroll
            for (int k2 = 0; k2 < 16; ++k2) {
                f16x8 wv = *(const f16x8*)(K2p + (size_t)k2 * (H * 2));
                float2 tv = *(const float2*)&ts[(q2 * 16 + k2) * 2];   // LDS broadcast
                a.x = fmaf(tv.x, (float)wv[0], fmaf(tv.y, (float)wv[1], a.x));
                a.y = fmaf(tv.x, (float)wv[2], fmaf(tv.y, (float)wv[3], a.y));
                a.z = fmaf(tv.x, (float)wv[4], fmaf(tv.y, (float)wv[5], a.z));
                a.w = fmaf(tv.x, (float)wv[6], fmaf(tv.y, (float)wv[7], a.w));
            }
            *(float4*)&red[q2 * 256 + j4K] = a;
        }
        __syncthreads();

        // ---- K2 combine + o*tanh + LayerNorm (one wave, 4 cols/lane) ----
        if (tid < 64) {
            float4 hp = kb24;
            #pragma unroll
            for (int q = 0; q < 16; ++q) {
                float4 p = *(float4*)&red[q * 256 + tid * 4];
                hp.x += p.x; hp.y += p.y; hp.z += p.z; hp.w += p.w;
            }
            float4 o = *(float4*)&gos[tid * 4];
            float4 u;
            u.x = o.x * tanh_f(hp.x); u.y = o.y * tanh_f(hp.y);
            u.z = o.z * tanh_f(hp.z); u.w = o.w * tanh_f(hp.w);
            float s1 = u.x + u.y + u.z + u.w;
            float s2 = u.x * u.x + u.y * u.y + u.z * u.z + u.w * u.w;
            #pragma unroll
            for (int off = 32; off > 0; off >>= 1) {
                s1 += __shfl_xor(s1, off);
                s2 += __shfl_xor(s2, off);
            }
            float mu   = s1 * (1.f / 256.f);
            float var  = fmaf(-mu, mu, s2 * (1.f / 256.f));
            float rstd = rsqrtf(var + 1e-5f);
            float4 hn;
            hn.x = (u.x - mu) * rstd * gam4.x + bet4.x;
            hn.y = (u.y - mu) * rstd * gam4.y + bet4.y;
            hn.z = (u.z - mu) * rstd * gam4.z + bet4.z;
            hn.w = (u.w - mu) * rstd * gam4.w + bet4.w;
            *(float4*)&hs[tid * 4] = hn;
            *(float4*)(yb + (size_t)t * H + tid * 4) = hn;
            if (t == T - 1) {
                *(float4*)(out + (size_t)B * T * H + (size_t)b * H + tid * 4) = hn;
                float4 c = *(float4*)&cs[tid * 4];
                *(float4*)(out + (size_t)B * T * H + (size_t)B * H + (size_t)b * H + tid * 4) = c;
            }
        }
        __syncthreads();  // protects red (reused next step) and hs (read by next phase G)
    }
}

extern "C" void kernel_launch(void* const* d_in, const int* in_sizes, int n_in,
                              void* d_out, int out_size, void* d_ws, size_t ws_size,
                              hipStream_t stream) {
    (void)in_sizes; (void)n_in; (void)out_size;
    if (ws_size < (size_t)(H2 / 2) * H * 4) return;  // need 256 KB for K2h

    const float* x     = (const float*)d_in[0];
    const float* Wi    = (const float*)d_in[1];
    const float* bi    = (const float*)d_in[2];
    const float* Wf    = (const float*)d_in[3];
    const float* bf    = (const float*)d_in[4];
    const float* Wc    = (const float*)d_in[5];
    const float* bc    = (const float*)d_in[6];
    const float* Wo    = (const float*)d_in[7];
    const float* bo    = (const float*)d_in[8];
    const float* Ui    = (const float*)d_in[9];
    const float* Uf    = (const float*)d_in[10];
    const float* Uc    = (const float*)d_in[11];
    const float* Uo    = (const float*)d_in[12];
    const float* K1    = (const float*)d_in[13];
    const float* kb1   = (const float*)d_in[14];
    const float* K2    = (const float*)d_in[15];
    const float* kb2   = (const float*)d_in[16];
    const float* gamma = (const float*)d_in[17];
    const float* beta  = (const float*)d_in[18];
    float* out = (float*)d_out;

    f16x2* K2h = (f16x2*)d_ws;

    pack_k2_kernel<<<dim3(256), dim3(256), 0, stream>>>(K2, K2h);
    scan_kernel<<<dim3(B), dim3(1024), 0, stream>>>(
        x, Wi, bi, Wf, bf, Wc, bc, Wo, bo,
        Ui, Uf, Uc, Uo, K1, kb1, (const _Float16*)K2h, kb2, gamma, beta, out);
}

// Round 5
// 39498.956 us; speedup vs baseline: 2.8834x; 2.8834x over previous
//
#include <hip/hip_runtime.h>

#define B 64
#define T 2048
#define D 128
#define H 256
#define H2 512
#define NP 4
#define CHUNK 8

// workspace: flags uint[64][16] (4 KB) then per-row data float[1024]:
//   [0..255] cbuf, [256..767] tsbuf, [768..1023] ubuf
#define WS_NEEDED (4096 + (size_t)B * 1024 * 4)

__device__ __forceinline__ float sigmoid_f(float x) { return 1.f / (1.f + __expf(-x)); }
__device__ __forceinline__ float tanh_f(float x) {
    float e = __expf(2.f * x);
    return 1.f - 2.f / (e + 1.f);
}

// NOTE: param names must not collide with member names .x/.y/.z/.w (token-pasting bug in r4)
#define FMA4(A_, S_, W_) \
    A_.x = fmaf(S_, W_.x, A_.x); A_.y = fmaf(S_, W_.y, A_.y); \
    A_.z = fmaf(S_, W_.z, A_.z); A_.w = fmaf(S_, W_.w, A_.w);

// 256 blocks = 64 rows x 4 column-parts; 512 threads; 1 block/CU (LDS-forced).
// U-quarter (128 VGPR) + K1-quarter (64 VGPR) register-resident, K2-quarter in LDS.
__global__ __launch_bounds__(512, 2) void scan_kernel(
    const float* __restrict__ x,
    const float* __restrict__ Wi, const float* __restrict__ bi,
    const float* __restrict__ Wf, const float* __restrict__ bf,
    const float* __restrict__ Wc, const float* __restrict__ bc,
    const float* __restrict__ Wo, const float* __restrict__ bo,
    const float* __restrict__ Ui, const float* __restrict__ Uf,
    const float* __restrict__ Uc, const float* __restrict__ Uo,
    const float* __restrict__ K1, const float* __restrict__ kb1,
    const float* __restrict__ K2, const float* __restrict__ kb2,
    const float* __restrict__ gamma, const float* __restrict__ beta,
    float* __restrict__ out,
    unsigned int* __restrict__ wsflags, float* __restrict__ wsdata)
{
    const int bid = blockIdx.x;
    const int b   = bid >> 2;
    const int p   = bid & 3;
    const int tid = threadIdx.x;

    __shared__ float k2lds[H2 * 64];      // 128 KB: K2[:, p*64..p*64+64)
    __shared__ float xw[CHUNK][256];      // 8 KB
    __shared__ float red[2048];           // 8 KB
    __shared__ float hs[H], cs[H], ts[H2], us[H], ga[256], gos[64];

    // ---- roles ----
    const int kq  = tid >> 6;                         // 0..7 (wave)
    const int grp = tid & 63;
    const int gG  = grp >> 4;                         // gate 0..3
    const int jG  = (grp & 15) * 4;                   // col-4 within part
    const int ks1 = ((tid >> 6) << 1) | ((tid >> 5) & 1);  // 0..15 (half-wave)
    const int mg1 = tid & 31;                         // K1 col group
    const int ks2 = tid >> 4;                         // 0..31
    const int jg2 = (tid & 15) * 4;                   // K2 col-4

    const float* Ug = (gG == 0) ? Ui : (gG == 1) ? Uf : (gG == 2) ? Uc : Uo;
    const float* Wg = (gG == 0) ? Wi : (gG == 1) ? Wf : (gG == 2) ? Wc : Wo;

    // ---- register-resident weights ----
    float4 uw[32];                                    // U: 32 k x 4 cols
    #pragma unroll
    for (int k = 0; k < 32; ++k)
        uw[k] = *(const float4*)(Ug + (size_t)(kq * 32 + k) * H + p * 64 + jG);

    float4 k1w[16];                                   // K1: 16 k x 4 cols
    #pragma unroll
    for (int k = 0; k < 16; ++k)
        k1w[k] = *(const float4*)(K1 + (size_t)(ks1 * 16 + k) * H2 + p * 128 + mg1 * 4);

    // ---- K2 quarter -> LDS ----
    for (int idx = tid; idx < H2 * 16; idx += 512) {
        int k = idx >> 4, jg = (idx & 15) * 4;
        *(float4*)&k2lds[k * 64 + jg] = *(const float4*)(K2 + (size_t)k * H + p * 64 + jg);
    }

    // ---- per-role constants ----
    float bcat = 0.f, kb1r = 0.f, kb2r = 0.f;
    float4 gam4, bet4;
    if (tid < 256) {
        const int g = tid >> 6, jj = tid & 63;
        const float* bp = (g == 0) ? bi : (g == 1) ? bf : (g == 2) ? bc : bo;
        bcat = bp[p * 64 + jj];
    }
    if (tid < 128) kb1r = kb1[p * 128 + tid];
    if (tid < 64) {
        kb2r = kb2[p * 64 + tid];
        gam4 = *(const float4*)(gamma + tid * 4);
        bet4 = *(const float4*)(beta + tid * 4);
    }

    if (tid < H) { hs[tid] = 0.f; cs[tid] = 0.f; }

    const float* xrow = x + (size_t)b * T * D;
    float* yb = out + (size_t)b * T * H;
    unsigned int* flagrow = wsflags + b * 16;
    float* rowptr = wsdata + (size_t)b * 1024;
    const int dqu = __builtin_amdgcn_readfirstlane(kq);   // uniform d-slice for x s_loads

    bool alive = true;   // spin-timeout latch (lanes 0..3 of wave 0)
    __syncthreads();

    for (int t = 0; t < T; ++t) {
        const int tt8 = t & (CHUNK - 1);
        const unsigned int seq = (unsigned int)(t + 1);

        // ============ phase P: x@W for 8 steps (once per chunk; W streamed) ============
        if (tt8 == 0) {
            const float* Wp = Wg + p * 64 + jG;
            #pragma unroll
            for (int pass = 0; pass < 2; ++pass) {
                float4 acc[4];
                #pragma unroll
                for (int r = 0; r < 4; ++r) acc[r] = make_float4(0.f, 0.f, 0.f, 0.f);
                #pragma unroll 4
                for (int dd = 0; dd < 16; ++dd) {
                    const int d = dqu * 16 + dd;
                    float4 w = *(const float4*)(Wp + (size_t)d * H);
                    #pragma unroll
                    for (int r = 0; r < 4; ++r) {
                        float xv = xrow[(size_t)(t + pass * 4 + r) * D + d];  // uniform -> s_load
                        FMA4(acc[r], xv, w);
                    }
                }
                #pragma unroll
                for (int r = 0; r < 4; ++r) {
                    *(float4*)&red[kq * 256 + grp * 4] = acc[r];
                    __syncthreads();
                    if (tid < 256) {
                        float s = bcat;
                        #pragma unroll
                        for (int q = 0; q < 8; ++q) s += red[q * 256 + tid];
                        xw[pass * 4 + r][tid] = s;
                    }
                    __syncthreads();
                }
            }
        }

        // ============ phase G: gate preacts from register-resident U ============
        {
            float4 a = make_float4(0.f, 0.f, 0.f, 0.f);
            #pragma unroll
            for (int k4 = 0; k4 < 8; ++k4) {
                float4 hv = *(const float4*)&hs[kq * 32 + k4 * 4];
                FMA4(a, hv.x, uw[k4 * 4 + 0]);
                FMA4(a, hv.y, uw[k4 * 4 + 1]);
                FMA4(a, hv.z, uw[k4 * 4 + 2]);
                FMA4(a, hv.w, uw[k4 * 4 + 3]);
            }
            *(float4*)&red[kq * 256 + grp * 4] = a;
        }
        __syncthreads();
        if (tid < 256) {
            float s = xw[tt8][tid];
            #pragma unroll
            for (int q = 0; q < 8; ++q) s += red[q * 256 + tid];
            ga[tid] = ((tid >> 6) == 2) ? tanh_f(s) : sigmoid_f(s);
        }
        __syncthreads();
        // ---- cell update + publish c-slice (wave 0) ----
        if (tid < 64) {
            float iv = ga[tid], fv = ga[64 + tid], gv = ga[128 + tid], ov = ga[192 + tid];
            float c = fmaf(fv, cs[p * 64 + tid], iv * gv);
            cs[p * 64 + tid] = c;
            gos[tid] = ov;
            __hip_atomic_store(rowptr + p * 64 + tid, c, __ATOMIC_RELAXED, __HIP_MEMORY_SCOPE_AGENT);
            if (tid == 0)
                __hip_atomic_store(flagrow + 0 + p, seq, __ATOMIC_RELEASE, __HIP_MEMORY_SCOPE_AGENT);
        }
        // ---- sync #1: full c ----
        if (tid < 64) {
            bool done = (tid >= NP) || !alive;
            int cnt = 0;
            while (!__all(done)) {
                if (!done) {
                    unsigned int v = __hip_atomic_load(flagrow + 0 + tid, __ATOMIC_ACQUIRE, __HIP_MEMORY_SCOPE_AGENT);
                    done = (v == seq);
                    if (++cnt > (1 << 22)) { alive = false; done = true; }
                }
            }
        }
        __syncthreads();
        if (tid < 256)
            cs[tid] = __hip_atomic_load(rowptr + tid, __ATOMIC_RELAXED, __HIP_MEMORY_SCOPE_AGENT);
        __syncthreads();

        // ============ phase K1: ts-slice from register-resident K1 ============
        {
            float4 a = make_float4(0.f, 0.f, 0.f, 0.f);
            #pragma unroll
            for (int k4 = 0; k4 < 4; ++k4) {
                float4 cv = *(const float4*)&cs[ks1 * 16 + k4 * 4];
                FMA4(a, cv.x, k1w[k4 * 4 + 0]);
                FMA4(a, cv.y, k1w[k4 * 4 + 1]);
                FMA4(a, cv.z, k1w[k4 * 4 + 2]);
                FMA4(a, cv.w, k1w[k4 * 4 + 3]);
            }
            *(float4*)&red[ks1 * 128 + mg1 * 4] = a;
        }
        __syncthreads();
        if (tid < 128) {
            float s = kb1r;
            #pragma unroll
            for (int q = 0; q < 16; ++q) s += red[q * 128 + tid];
            float tv = tanh_f(s);
            ts[p * 128 + tid] = tv;
            __hip_atomic_store(rowptr + 256 + p * 128 + tid, tv, __ATOMIC_RELAXED, __HIP_MEMORY_SCOPE_AGENT);
        }
        __syncthreads();   // drains all waves' stores before the flag release
        if (tid == 0)
            __hip_atomic_store(flagrow + 4 + p, seq, __ATOMIC_RELEASE, __HIP_MEMORY_SCOPE_AGENT);
        // ---- sync #2: full ts ----
        if (tid < 64) {
            bool done = (tid >= NP) || !alive;
            int cnt = 0;
            while (!__all(done)) {
                if (!done) {
                    unsigned int v = __hip_atomic_load(flagrow + 4 + tid, __ATOMIC_ACQUIRE, __HIP_MEMORY_SCOPE_AGENT);
                    done = (v == seq);
                    if (++cnt > (1 << 22)) { alive = false; done = true; }
                }
            }
        }
        __syncthreads();
        ts[tid] = __hip_atomic_load(rowptr + 256 + tid, __ATOMIC_RELAXED, __HIP_MEMORY_SCOPE_AGENT);
        __syncthreads();

        // ============ phase K2: h_pre-slice from LDS-resident K2 ============
        {
            float4 a = make_float4(0.f, 0.f, 0.f, 0.f);
            #pragma unroll
            for (int k4 = 0; k4 < 4; ++k4) {
                float4 tv = *(const float4*)&ts[ks2 * 16 + k4 * 4];
                float4 w0 = *(const float4*)&k2lds[(ks2 * 16 + k4 * 4 + 0) * 64 + jg2];
                float4 w1 = *(const float4*)&k2lds[(ks2 * 16 + k4 * 4 + 1) * 64 + jg2];
                float4 w2 = *(const float4*)&k2lds[(ks2 * 16 + k4 * 4 + 2) * 64 + jg2];
                float4 w3 = *(const float4*)&k2lds[(ks2 * 16 + k4 * 4 + 3) * 64 + jg2];
                FMA4(a, tv.x, w0);
                FMA4(a, tv.y, w1);
                FMA4(a, tv.z, w2);
                FMA4(a, tv.w, w3);
            }
            *(float4*)&red[ks2 * 64 + jg2] = a;
        }
        __syncthreads();
        if (tid < 64) {
            float s = kb2r;
            #pragma unroll
            for (int q = 0; q < 32; ++q) s += red[q * 64 + tid];
            float u = gos[tid] * tanh_f(s);
            us[p * 64 + tid] = u;
            __hip_atomic_store(rowptr + 768 + p * 64 + tid, u, __ATOMIC_RELAXED, __HIP_MEMORY_SCOPE_AGENT);
            if (tid == 0)
                __hip_atomic_store(flagrow + 8 + p, seq, __ATOMIC_RELEASE, __HIP_MEMORY_SCOPE_AGENT);
        }
        // ---- sync #3: full u ----
        if (tid < 64) {
            bool done = (tid >= NP) || !alive;
            int cnt = 0;
            while (!__all(done)) {
                if (!done) {
                    unsigned int v = __hip_atomic_load(flagrow + 8 + tid, __ATOMIC_ACQUIRE, __HIP_MEMORY_SCOPE_AGENT);
                    done = (v == seq);
                    if (++cnt > (1 << 22)) { alive = false; done = true; }
                }
            }
        }
        __syncthreads();
        if (tid < 256)
            us[tid] = __hip_atomic_load(rowptr + 768 + tid, __ATOMIC_RELAXED, __HIP_MEMORY_SCOPE_AGENT);
        __syncthreads();

        // ============ LayerNorm (redundant across the 4 blocks -> full h locally) ============
        if (tid < 64) {
            float4 u4 = *(const float4*)&us[tid * 4];
            float s1 = u4.x + u4.y + u4.z + u4.w;
            float s2 = u4.x * u4.x + u4.y * u4.y + u4.z * u4.z + u4.w * u4.w;
            #pragma unroll
            for (int off = 32; off > 0; off >>= 1) {
                s1 += __shfl_xor(s1, off);
                s2 += __shfl_xor(s2, off);
            }
            float mu   = s1 * (1.f / 256.f);
            float var  = fmaf(-mu, mu, s2 * (1.f / 256.f));
            float rstd = rsqrtf(var + 1e-5f);
            float4 hn;
            hn.x = (u4.x - mu) * rstd * gam4.x + bet4.x;
            hn.y = (u4.y - mu) * rstd * gam4.y + bet4.y;
            hn.z = (u4.z - mu) * rstd * gam4.z + bet4.z;
            hn.w = (u4.w - mu) * rstd * gam4.w + bet4.w;
            *(float4*)&hs[tid * 4] = hn;
            if ((tid >> 4) == p) {   // own column slice only
                *(float4*)(yb + (size_t)t * H + tid * 4) = hn;
                if (t == T - 1) {
                    *(float4*)(out + (size_t)B * T * H + (size_t)b * H + tid * 4) = hn;
                    float4 c4 = *(const float4*)&cs[tid * 4];
                    *(float4*)(out + (size_t)B * T * H + (size_t)B * H + (size_t)b * H + tid * 4) = c4;
                }
            }
        }
        __syncthreads();   // hs ready for next step's phase G
    }
}

extern "C" void kernel_launch(void* const* d_in, const int* in_sizes, int n_in,
                              void* d_out, int out_size, void* d_ws, size_t ws_size,
                              hipStream_t stream) {
    (void)in_sizes; (void)n_in; (void)out_size;
    if (ws_size < WS_NEEDED) return;

    const float* x     = (const float*)d_in[0];
    const float* Wi    = (const float*)d_in[1];
    const float* bi    = (const float*)d_in[2];
    const float* Wf    = (const float*)d_in[3];
    const float* bf    = (const float*)d_in[4];
    const float* Wc    = (const float*)d_in[5];
    const float* bc    = (const float*)d_in[6];
    const float* Wo    = (const float*)d_in[7];
    const float* bo    = (const float*)d_in[8];
    const float* Ui    = (const float*)d_in[9];
    const float* Uf    = (const float*)d_in[10];
    const float* Uc    = (const float*)d_in[11];
    const float* Uo    = (const float*)d_in[12];
    const float* K1    = (const float*)d_in[13];
    const float* kb1   = (const float*)d_in[14];
    const float* K2    = (const float*)d_in[15];
    const float* kb2   = (const float*)d_in[16];
    const float* gamma = (const float*)d_in[17];
    const float* beta  = (const float*)d_in[18];
    float* out = (float*)d_out;

    unsigned int* wsflags = (unsigned int*)d_ws;
    float* wsdata = (float*)((char*)d_ws + 4096);

    scan_kernel<<<dim3(B * NP), dim3(512), 0, stream>>>(
        x, Wi, bi, Wf, bf, Wc, bc, Wo, bo,
        Ui, Uf, Uc, Uo, K1, kb1, K2, kb2, gamma, beta, out,
        wsflags, wsdata);
}